// Round 5
// baseline (256.373 us; speedup 1.0000x reference)
//
#include <hip/hip_runtime.h>
#include <hip/hip_bf16.h>

#define M_TOTAL 16384
#define KDIM 2048
#define NDIM 2048
#define NEXP 8
#define BM 256
#define BN 128
#define BK 32
#define RT_MAX 71            // 16384/256 + 7 boundary extras
#define CT 16                // 2048/128 col tiles
#define NWG (RT_MAX * CT)    // 1136 = 8 * 142
#define BUFB 24576           // (256+128)*32*2 bytes per K-tile buffer

typedef __attribute__((ext_vector_type(8))) __bf16 bf16x8;
typedef __attribute__((ext_vector_type(4))) float f32x4;

__device__ inline int minI(int a, int b) { return a < b ? a : b; }

__device__ inline bf16x8 cvt8(float4 a, float4 b) {
  bf16x8 r;
  r[0] = (__bf16)a.x; r[1] = (__bf16)a.y; r[2] = (__bf16)a.z; r[3] = (__bf16)a.w;
  r[4] = (__bf16)b.x; r[5] = (__bf16)b.y; r[6] = (__bf16)b.z; r[7] = (__bf16)b.w;
  return r;
}

__device__ inline void gload16(const void* g, void* l) {
  __builtin_amdgcn_global_load_lds(
      (const __attribute__((address_space(1))) void*)g,
      (__attribute__((address_space(3))) void*)l, 16, 0, 0);
}

// ---------------- fp32 -> bf16 conversion (x then W) ----------------
__global__ __launch_bounds__(256) void cvt_both(
    const float* __restrict__ x, const float* __restrict__ w,
    bf16x8* __restrict__ xb, bf16x8* __restrict__ wb) {
  const int NX = (M_TOTAL * KDIM) / 8;
  const int NW = (NEXP * NDIM * KDIM) / 8;
  const int stride = gridDim.x * blockDim.x;
  for (int i = blockIdx.x * blockDim.x + threadIdx.x; i < NX + NW; i += stride) {
    const float4* src = (i < NX) ? ((const float4*)x + (size_t)i * 2)
                                 : ((const float4*)w + (size_t)(i - NX) * 2);
    float4 a = src[0], b = src[1];
    bf16x8 c = cvt8(a, b);
    if (i < NX) xb[i] = c; else wb[i - NX] = c;
  }
}

// ---------------- grouped GEMM: 256x128 tile, BK=32, 3 LDS buffers (72KB)
// -> 2 blocks/CU co-resident, 4 waves/SIMD. Counted vmcnt(3), 1 barrier/tile.
// Swizzle: logical k-chunk c stored at phys p = c ^ ((row>>1)&3), applied by
// pre-swizzling the per-lane GLOBAL source column (LDS dest stays linear).
__global__ __launch_bounds__(512, 4) void moe_gemm_cores(
    const __hip_bfloat16* __restrict__ xb, const __hip_bfloat16* __restrict__ wb,
    const int* __restrict__ ms, float* __restrict__ out) {
  __shared__ __align__(16) char lds[3 * BUFB];

  // bijective XCD swizzle (NWG = 1136 = 8*142); consecutive wg share row-tile
  const int orig = blockIdx.x;
  const int wg = (orig & 7) * (NWG / 8) + (orig >> 3);
  const int bt = wg >> 4;     // row-tile 0..70
  const int ntile = wg & 15;  // col-tile 0..15

  // ---- map bt -> (expert e, row0, rows) ----
  int sizes[NEXP];
#pragma unroll
  for (int i = 0; i < NEXP; ++i) sizes[i] = ms[i];
  int e = 0, row0 = 0, rows = 0, acc_t = 0, start = 0;
  bool found = false;
#pragma unroll
  for (int i = 0; i < NEXP; ++i) {
    int nt = (sizes[i] + BM - 1) >> 8;
    if (!found && bt < acc_t + nt) {
      found = true; e = i;
      int tt = bt - acc_t;
      row0 = start + tt * BM;
      rows = minI(sizes[i] - tt * BM, BM);
    }
    acc_t += nt; start += sizes[i];
  }
  if (!found) return;

  const int tid = threadIdx.x;
  const int lane = tid & 63;
  const int wave = tid >> 6;
  const int wr = wave >> 1, wc = wave & 1;  // 4x2 waves, 64x64 out each
  const int col0 = ntile * BN;

  // ---- staging: per tile 3 gload16/thread (A rows 0-127, A rows 128-255, B) ----
  const int rwh = wave * 16 + (lane >> 2);                   // 0..127
  const int colel = (((lane & 3) ^ ((lane >> 3) & 3)) << 3); // pre-swizzled k col
  const __hip_bfloat16* aS0 = xb + (size_t)minI(row0 + rwh, M_TOTAL - 1) * KDIM + colel;
  const __hip_bfloat16* aS1 = xb + (size_t)minI(row0 + 128 + rwh, M_TOTAL - 1) * KDIM + colel;
  const __hip_bfloat16* wbase = wb + (size_t)e * NDIM * KDIM;
  const __hip_bfloat16* bS = wbase + (size_t)(col0 + rwh) * KDIM + colel;

  // ---- fragment read byte offsets (within a buffer), swizzled ----
  const int fr = lane & 15, fc = lane >> 4;
  int offA[4], offB[4];
#pragma unroll
  for (int mt = 0; mt < 4; ++mt) {
    int r = wr * 64 + mt * 16 + fr;
    offA[mt] = r * 64 + ((fc ^ ((r >> 1) & 3)) << 4);
  }
#pragma unroll
  for (int nt = 0; nt < 4; ++nt) {
    int r = wc * 64 + nt * 16 + fr;
    offB[nt] = 16384 + r * 64 + ((fc ^ ((r >> 1) & 3)) << 4);
  }

  f32x4 acc[4][4];
  const f32x4 zero = {0.f, 0.f, 0.f, 0.f};
#pragma unroll
  for (int i = 0; i < 4; ++i)
#pragma unroll
    for (int j = 0; j < 4; ++j) acc[i][j] = zero;

#define ISSUE3(T, BI) { char* b_ = lds + (BI) * BUFB + wave * 1024; \
    gload16(aS0 + (size_t)(T) * BK, b_); \
    gload16(aS1 + (size_t)(T) * BK, b_ + 8192); \
    gload16(bS + (size_t)(T) * BK, b_ + 16384); }

#define TILE(T, BR, BI, VM, DOI) { \
    asm volatile("s_waitcnt " VM ::: "memory"); \
    __builtin_amdgcn_s_barrier(); \
    if (DOI) ISSUE3((T) + 2, BI); \
    const char* bb_ = lds + (BR) * BUFB; \
    bf16x8 af[4], bv[4]; \
    _Pragma("unroll") for (int mt = 0; mt < 4; ++mt) \
      af[mt] = *(const bf16x8*)(bb_ + offA[mt]); \
    _Pragma("unroll") for (int nt = 0; nt < 4; ++nt) \
      bv[nt] = *(const bf16x8*)(bb_ + offB[nt]); \
    __builtin_amdgcn_s_setprio(1); \
    _Pragma("unroll") for (int mt = 0; mt < 4; ++mt) \
      _Pragma("unroll") for (int nt = 0; nt < 4; ++nt) \
        acc[mt][nt] = __builtin_amdgcn_mfma_f32_16x16x32_bf16( \
            af[mt], bv[nt], acc[mt][nt], 0, 0, 0); \
    __builtin_amdgcn_s_setprio(0); }

  // prologue: tiles 0,1 in flight (6 loads/thread)
  ISSUE3(0, 0)
  ISSUE3(1, 1)

  for (int tp = 0; tp < 20; ++tp) {
    const int t = tp * 3;
    TILE(t,     0, 2, "vmcnt(3)", true);
    TILE(t + 1, 1, 0, "vmcnt(3)", true);
    TILE(t + 2, 2, 1, "vmcnt(3)", true);
  }
  TILE(60, 0, 2, "vmcnt(3)", true);
  TILE(61, 1, 0, "vmcnt(3)", true);
  TILE(62, 2, 1, "vmcnt(3)", false);
  TILE(63, 0, 0, "vmcnt(0)", false);

#undef TILE
#undef ISSUE3

  // ---- epilogue: C/D layout col=lane&15, row=(lane>>4)*4+j ----
  const int er = (lane >> 4) * 4;
#pragma unroll
  for (int mt = 0; mt < 4; ++mt) {
#pragma unroll
    for (int j = 0; j < 4; ++j) {
      int r = wr * 64 + mt * 16 + er + j;
      if (r < rows) {
        float* op = out + (size_t)(row0 + r) * NDIM + col0 + wc * 64 + (lane & 15);
#pragma unroll
        for (int nt = 0; nt < 4; ++nt) op[nt * 16] = acc[mt][nt][j];
      }
    }
  }
}

// ---------------- fallback: direct fp32, reg-staged ----------------
__global__ __launch_bounds__(256) void moe_gemm_f32(
    const float* __restrict__ x, const float* __restrict__ w,
    const int* __restrict__ ms, float* __restrict__ out) {
  __shared__ __align__(16) char As[128 * 64 * 2];
  __shared__ __align__(16) char Bs[128 * 64 * 2];
  int sizes[NEXP];
#pragma unroll
  for (int i = 0; i < NEXP; ++i) sizes[i] = ms[i];
  const int bt = blockIdx.y;
  int e = 0, row0 = 0, rows = 0, acc_t = 0, start = 0;
  bool found = false;
#pragma unroll
  for (int i = 0; i < NEXP; ++i) {
    int nt = (sizes[i] + 127) >> 7;
    if (!found && bt < acc_t + nt) {
      found = true; e = i;
      int tt = bt - acc_t;
      row0 = start + tt * 128;
      rows = minI(sizes[i] - tt * 128, 128);
    }
    acc_t += nt; start += sizes[i];
  }
  if (!found) return;
  const int tid = threadIdx.x;
  const int lane = tid & 63;
  const int wave = tid >> 6;
  const int wm = wave >> 1, wn = wave & 1;
  const int col0 = blockIdx.x * 128;
  const float* wbase = w + (size_t)e * (size_t)NDIM * KDIM;
  const int sr = tid >> 1;
  const int sh = tid & 1;
  const float* aptr = x + (size_t)(row0 + sr) * KDIM + sh * 32;
  const float* bptr = wbase + (size_t)(col0 + sr) * KDIM + sh * 32;
  const bool aval = (sr < rows);
  f32x4 acc[4][4];
  const f32x4 zero = {0.f, 0.f, 0.f, 0.f};
#pragma unroll
  for (int i = 0; i < 4; ++i)
#pragma unroll
    for (int j = 0; j < 4; ++j) acc[i][j] = zero;
  for (int kb = 0; kb < KDIM / 64; ++kb) {
    {
      float4 v[8];
      if (aval) {
        const float4* p = (const float4*)(aptr + kb * 64);
#pragma unroll
        for (int j = 0; j < 8; ++j) v[j] = p[j];
      } else {
#pragma unroll
        for (int j = 0; j < 8; ++j) v[j] = make_float4(0.f, 0.f, 0.f, 0.f);
      }
#pragma unroll
      for (int j = 0; j < 4; ++j) {
        bf16x8 c = cvt8(v[2 * j], v[2 * j + 1]);
        int chunk = (sh * 4 + j) ^ (sr & 7);
        *(bf16x8*)(As + sr * 128 + chunk * 16) = c;
      }
    }
    {
      const float4* p = (const float4*)(bptr + kb * 64);
      float4 u[8];
#pragma unroll
      for (int j = 0; j < 8; ++j) u[j] = p[j];
#pragma unroll
      for (int j = 0; j < 4; ++j) {
        bf16x8 c = cvt8(u[2 * j], u[2 * j + 1]);
        int chunk = (sh * 4 + j) ^ (sr & 7);
        *(bf16x8*)(Bs + sr * 128 + chunk * 16) = c;
      }
    }
    __syncthreads();
#pragma unroll
    for (int ks = 0; ks < 2; ++ks) {
      bf16x8 afr[4], bfv[4];
#pragma unroll
      for (int mt = 0; mt < 4; ++mt) {
        int r = wm * 64 + mt * 16 + (lane & 15);
        int chunk = (ks * 4 + (lane >> 4)) ^ (r & 7);
        afr[mt] = *(const bf16x8*)(As + r * 128 + chunk * 16);
      }
#pragma unroll
      for (int nt = 0; nt < 4; ++nt) {
        int r = wn * 64 + nt * 16 + (lane & 15);
        int chunk = (ks * 4 + (lane >> 4)) ^ (r & 7);
        bfv[nt] = *(const bf16x8*)(Bs + r * 128 + chunk * 16);
      }
#pragma unroll
      for (int mt = 0; mt < 4; ++mt)
#pragma unroll
        for (int nt = 0; nt < 4; ++nt)
          acc[mt][nt] = __builtin_amdgcn_mfma_f32_16x16x32_bf16(
              afr[mt], bfv[nt], acc[mt][nt], 0, 0, 0);
    }
    __syncthreads();
  }
#pragma unroll
  for (int mt = 0; mt < 4; ++mt) {
#pragma unroll
    for (int j = 0; j < 4; ++j) {
      int r = wm * 64 + mt * 16 + (lane >> 4) * 4 + j;
      if (r < rows) {
        float* op = out + (size_t)(row0 + r) * NDIM + col0 + wn * 64 + (lane & 15);
#pragma unroll
        for (int nt = 0; nt < 4; ++nt) op[nt * 16] = acc[mt][nt][j];
      }
    }
  }
}

extern "C" void kernel_launch(void* const* d_in, const int* in_sizes, int n_in,
                              void* d_out, int out_size, void* d_ws, size_t ws_size,
                              hipStream_t stream) {
  const float* x = (const float*)d_in[0];
  const float* w = (const float*)d_in[1];
  const int* ms = (const int*)d_in[2];
  float* out = (float*)d_out;
  const size_t nx = (size_t)M_TOTAL * KDIM;
  const size_t nw = (size_t)NEXP * NDIM * KDIM;
  const size_t need = (nx + nw) * sizeof(__hip_bfloat16);
  if (ws_size >= need) {
    __hip_bfloat16* xb = (__hip_bfloat16*)d_ws;
    __hip_bfloat16* wb = xb + nx;
    cvt_both<<<2048, 256, 0, stream>>>(x, w, (bf16x8*)xb, (bf16x8*)wb);
    moe_gemm_cores<<<dim3(NWG), dim3(512), 0, stream>>>(xb, wb, ms, out);
  } else {
    moe_gemm_f32<<<dim3(16, 135), dim3(256), 0, stream>>>(x, w, ms, out);
  }
}

// Round 6
// 239.126 us; speedup vs baseline: 1.0721x; 1.0721x over previous
//
#include <hip/hip_runtime.h>
#include <hip/hip_bf16.h>

#define M_TOTAL 16384
#define KDIM 2048
#define NDIM 2048
#define NEXP 8
#define BM 256
#define BN 256
#define BK 64
#define MAX_ROW_TILES 71  // 16384/256 + 7 boundary extras
#define NWG (MAX_ROW_TILES * 8)

typedef __attribute__((ext_vector_type(8))) __bf16 bf16x8;
typedef __attribute__((ext_vector_type(4))) float f32x4;

__device__ inline int minI(int a, int b) { return a < b ? a : b; }

__device__ inline bf16x8 cvt8(float4 a, float4 b) {
  bf16x8 r;
  r[0] = (__bf16)a.x; r[1] = (__bf16)a.y; r[2] = (__bf16)a.z; r[3] = (__bf16)a.w;
  r[4] = (__bf16)b.x; r[5] = (__bf16)b.y; r[6] = (__bf16)b.z; r[7] = (__bf16)b.w;
  return r;
}

__device__ inline void gload16(const void* g, void* l) {
  __builtin_amdgcn_global_load_lds(
      (const __attribute__((address_space(1))) void*)g,
      (__attribute__((address_space(3))) void*)l, 16, 0, 0);
}

// ---------------- fp32 -> bf16 conversion (x then W) ----------------
__global__ __launch_bounds__(256) void cvt_both(
    const float* __restrict__ x, const float* __restrict__ w,
    bf16x8* __restrict__ xb, bf16x8* __restrict__ wb) {
  const int NX = (M_TOTAL * KDIM) / 8;
  const int NW = (NEXP * NDIM * KDIM) / 8;
  const int stride = gridDim.x * blockDim.x;
  for (int i = blockIdx.x * blockDim.x + threadIdx.x; i < NX + NW; i += stride) {
    const float4* src = (i < NX) ? ((const float4*)x + (size_t)i * 2)
                                 : ((const float4*)w + (size_t)(i - NX) * 2);
    float4 a = src[0], b = src[1];
    bf16x8 c = cvt8(a, b);
    if (i < NX) xb[i] = c; else wb[i - NX] = c;
  }
}

// ---------------- grouped GEMM: 256x256 tile, BK=64, 8-phase schedule ----------------
// LDS: 2 buffers x 64KB. Buffer d at d*65536: A rows 0-255 (128B/row) at +0,
// B rows 0-255 at +32768. Row = 8 chunks of 16B; logical chunk c stored at
// phys p = c ^ (row&7) (zero-conflict: 2/bank per 16-lane subphase).
// gload_lds dest is linear; swizzle applied by pre-swizzled per-lane global col.
// Staging units = 64 rows (8KB = 512 thr x 16B). Calendar (iter computes t@buf0,
// t+1@buf1): ph1: t+1 B23 | ph2: t+1 AL | ph3: t+1 AH | ph4: t+2 B01 |
// ph5: t+2 B23 | ph6: t+2 AL | ph7: t+2 AH | ph8: t+3 B01. Every unit's LDS
// region is last-read strictly before its issue phase. Uniform vmcnt(4) at
// end of phases 1,4,5,8 (queue-simulated, steady state + prologue identical).
__global__ __launch_bounds__(512, 2) void moe_gemm_8p(
    const __hip_bfloat16* __restrict__ xb, const __hip_bfloat16* __restrict__ wb,
    const int* __restrict__ ms, float* __restrict__ out) {
  __shared__ __align__(16) char lds[131072];

  // bijective XCD swizzle (NWG = 568 = 8*71)
  const int orig = blockIdx.x;
  const int wg = (orig & 7) * MAX_ROW_TILES + (orig >> 3);
  const int bt = wg >> 3;
  const int ntile = wg & 7;

  // ---- map bt -> (expert e, row0, rows) ----
  int sizes[NEXP];
#pragma unroll
  for (int i = 0; i < NEXP; ++i) sizes[i] = ms[i];
  int e = 0, row0 = 0, rows = 0, acc_t = 0, start = 0;
  bool found = false;
#pragma unroll
  for (int i = 0; i < NEXP; ++i) {
    int nt = (sizes[i] + BM - 1) >> 8;
    if (!found && bt < acc_t + nt) {
      found = true; e = i;
      int tt = bt - acc_t;
      row0 = start + tt * BM;
      rows = minI(sizes[i] - tt * BM, BM);
    }
    acc_t += nt; start += sizes[i];
  }
  if (!found) return;

  const int tid = threadIdx.x;
  const int lane = tid & 63;
  const int wave = tid >> 6;
  const int wr = wave >> 2, wc = wave & 3;  // 2x4 waves, 128x64 out each
  const int col0 = ntile * BN;

  // ---- staging thread coords: unit = 64 rows x 128B; thread t -> row t>>3,
  // phys chunk t&7; logical chunk = (t&7)^(row&7) -> pre-swizzled source col.
  const int urow = tid >> 3;
  const int colel = (((tid & 7) ^ ((tid >> 3) & 7)) << 3);
  const __hip_bfloat16* wbase = wb + (size_t)e * NDIM * KDIM;
  const __hip_bfloat16* aP00 = xb + (size_t)minI(row0 +   0 + urow, M_TOTAL - 1) * KDIM + colel;
  const __hip_bfloat16* aP01 = xb + (size_t)minI(row0 +  64 + urow, M_TOTAL - 1) * KDIM + colel;
  const __hip_bfloat16* aP10 = xb + (size_t)minI(row0 + 128 + urow, M_TOTAL - 1) * KDIM + colel;
  const __hip_bfloat16* aP11 = xb + (size_t)minI(row0 + 192 + urow, M_TOTAL - 1) * KDIM + colel;
  const __hip_bfloat16* bP0 = wbase + (size_t)(col0 +   0 + urow) * KDIM + colel;
  const __hip_bfloat16* bP1 = wbase + (size_t)(col0 +  64 + urow) * KDIM + colel;
  const __hip_bfloat16* bP2 = wbase + (size_t)(col0 + 128 + urow) * KDIM + colel;
  const __hip_bfloat16* bP3 = wbase + (size_t)(col0 + 192 + urow) * KDIM + colel;

  // ---- fragment read lane terms (swizzled; phys = (ks*4+fc) ^ (fr&7)) ----
  const int fr = lane & 15, fc = lane >> 4;
  const int swz0 = fr * 128 + (((fc) ^ (fr & 7)) << 4);      // ks=0
  const int swz1 = fr * 128 + (((4 + fc) ^ (fr & 7)) << 4);  // ks=1
  const int aBase = wr * 16384;
  const int bBase = 32768 + (wc >> 1) * 16384 + (wc & 1) * 8192;

  f32x4 acc[8][4];
  const f32x4 zero = {0.f, 0.f, 0.f, 0.f};
#pragma unroll
  for (int i = 0; i < 8; ++i)
#pragma unroll
    for (int j = 0; j < 4; ++j) acc[i][j] = zero;

  bf16x8 af[4], bv[4];

#define ST_A(D, H, L, KK) gload16(aP##H##L + (size_t)(KK) * BK, \
    lds + (D) * 65536 + ((H) * 2 + (L)) * 8192 + wave * 1024);
#define ST_B(D, Q, KK) gload16(bP##Q + (size_t)(KK) * BK, \
    lds + (D) * 65536 + 32768 + (Q) * 8192 + wave * 1024);
#define VM4 asm volatile("s_waitcnt vmcnt(4)" ::: "memory");
#define VM2 asm volatile("s_waitcnt vmcnt(2)" ::: "memory");
#define VM0 asm volatile("s_waitcnt vmcnt(0)" ::: "memory");

#define PHASE(D, MH, SWZ, LOADB, STAGEBLK, WAITBLK) { \
    _Pragma("unroll") for (int mt = 0; mt < 4; ++mt) \
      af[mt] = *(const bf16x8*)(lds + (D) * 65536 + aBase + ((MH) * 4 + mt) * 2048 + SWZ); \
    if (LOADB) { _Pragma("unroll") for (int nt = 0; nt < 4; ++nt) \
      bv[nt] = *(const bf16x8*)(lds + (D) * 65536 + bBase + nt * 2048 + SWZ); } \
    STAGEBLK \
    __builtin_amdgcn_s_barrier(); \
    asm volatile("s_waitcnt lgkmcnt(0)" ::: "memory"); \
    __builtin_amdgcn_s_setprio(1); \
    _Pragma("unroll") for (int mt = 0; mt < 4; ++mt) \
      _Pragma("unroll") for (int nt = 0; nt < 4; ++nt) \
        acc[(MH) * 4 + mt][nt] = __builtin_amdgcn_mfma_f32_16x16x32_bf16( \
            af[mt], bv[nt], acc[(MH) * 4 + mt][nt], 0, 0, 0); \
    __builtin_amdgcn_s_setprio(0); \
    WAITBLK \
    asm volatile("" ::: "memory"); \
    __builtin_amdgcn_s_barrier(); \
    asm volatile("" ::: "memory"); \
  }

  // ---- prologue: K0 fully (B0-3, AL, AH) + K1 B01 = 10 units; vmcnt(4)
  // leaves [K0 AH x2, K1 B01 x2] = exact steady-state carry-in. ----
  ST_B(0, 0, 0) ST_B(0, 1, 0) ST_B(0, 2, 0) ST_B(0, 3, 0)
  ST_A(0, 0, 0, 0) ST_A(0, 1, 0, 0)   // AL: local rows 0-63 of each half
  ST_A(0, 0, 1, 0) ST_A(0, 1, 1, 0)   // AH: local rows 64-127
  ST_B(1, 0, 1) ST_B(1, 1, 1)
  VM4
  __builtin_amdgcn_s_barrier();

  for (int i = 0; i < 15; ++i) {
    const int t = 2 * i;
    PHASE(0, 0, swz0, true,  { ST_B(1, 2, t + 1) ST_B(1, 3, t + 1) }, VM4)
    PHASE(0, 1, swz0, false, { ST_A(1, 0, 0, t + 1) ST_A(1, 1, 0, t + 1) }, )
    PHASE(0, 0, swz1, true,  { ST_A(1, 0, 1, t + 1) ST_A(1, 1, 1, t + 1) }, )
    PHASE(0, 1, swz1, false, { ST_B(0, 0, t + 2) ST_B(0, 1, t + 2) }, VM4)
    PHASE(1, 0, swz0, true,  { ST_B(0, 2, t + 2) ST_B(0, 3, t + 2) }, VM4)
    PHASE(1, 1, swz0, false, { ST_A(0, 0, 0, t + 2) ST_A(0, 1, 0, t + 2) }, )
    PHASE(1, 0, swz1, true,  { ST_A(0, 0, 1, t + 2) ST_A(0, 1, 1, t + 2) }, )
    PHASE(1, 1, swz1, false, { ST_B(1, 0, t + 3) ST_B(1, 1, t + 3) }, VM4)
  }
  // ---- peeled last iteration (t=30): finish staging K31, drain 4/2/0 ----
  PHASE(0, 0, swz0, true,  { ST_B(1, 2, 31) ST_B(1, 3, 31) }, VM4)
  PHASE(0, 1, swz0, false, { ST_A(1, 0, 0, 31) ST_A(1, 1, 0, 31) }, )
  PHASE(0, 0, swz1, true,  { ST_A(1, 0, 1, 31) ST_A(1, 1, 1, 31) }, )
  PHASE(0, 1, swz1, false, { }, VM2)
  PHASE(1, 0, swz0, true,  { }, VM0)
  PHASE(1, 1, swz0, false, { }, )
  PHASE(1, 0, swz1, true,  { }, )
  PHASE(1, 1, swz1, false, { }, )

#undef PHASE
#undef VM0
#undef VM2
#undef VM4
#undef ST_B
#undef ST_A

  // ---- epilogue: C/D layout col=lane&15, row=(lane>>4)*4+j ----
  const int er = (lane >> 4) * 4;
#pragma unroll
  for (int mt = 0; mt < 8; ++mt) {
#pragma unroll
    for (int j = 0; j < 4; ++j) {
      int r = wr * 128 + mt * 16 + er + j;
      if (r < rows) {
        float* op = out + (size_t)(row0 + r) * NDIM + col0 + wc * 64 + (lane & 15);
#pragma unroll
        for (int nt = 0; nt < 4; ++nt) op[nt * 16] = acc[mt][nt][j];
      }
    }
  }
}

// ---------------- fallback: direct fp32, reg-staged ----------------
__global__ __launch_bounds__(256) void moe_gemm_f32(
    const float* __restrict__ x, const float* __restrict__ w,
    const int* __restrict__ ms, float* __restrict__ out) {
  __shared__ __align__(16) char As[128 * 64 * 2];
  __shared__ __align__(16) char Bs[128 * 64 * 2];
  int sizes[NEXP];
#pragma unroll
  for (int i = 0; i < NEXP; ++i) sizes[i] = ms[i];
  const int bt = blockIdx.y;
  int e = 0, row0 = 0, rows = 0, acc_t = 0, start = 0;
  bool found = false;
#pragma unroll
  for (int i = 0; i < NEXP; ++i) {
    int nt = (sizes[i] + 127) >> 7;
    if (!found && bt < acc_t + nt) {
      found = true; e = i;
      int tt = bt - acc_t;
      row0 = start + tt * 128;
      rows = minI(sizes[i] - tt * 128, 128);
    }
    acc_t += nt; start += sizes[i];
  }
  if (!found) return;
  const int tid = threadIdx.x;
  const int lane = tid & 63;
  const int wave = tid >> 6;
  const int wm = wave >> 1, wn = wave & 1;
  const int col0 = blockIdx.x * 128;
  const float* wbase = w + (size_t)e * (size_t)NDIM * KDIM;
  const int sr = tid >> 1;
  const int sh = tid & 1;
  const float* aptr = x + (size_t)(row0 + sr) * KDIM + sh * 32;
  const float* bptr = wbase + (size_t)(col0 + sr) * KDIM + sh * 32;
  const bool aval = (sr < rows);
  f32x4 acc[4][4];
  const f32x4 zero = {0.f, 0.f, 0.f, 0.f};
#pragma unroll
  for (int i = 0; i < 4; ++i)
#pragma unroll
    for (int j = 0; j < 4; ++j) acc[i][j] = zero;
  for (int kb = 0; kb < KDIM / 64; ++kb) {
    {
      float4 v[8];
      if (aval) {
        const float4* p = (const float4*)(aptr + kb * 64);
#pragma unroll
        for (int j = 0; j < 8; ++j) v[j] = p[j];
      } else {
#pragma unroll
        for (int j = 0; j < 8; ++j) v[j] = make_float4(0.f, 0.f, 0.f, 0.f);
      }
#pragma unroll
      for (int j = 0; j < 4; ++j) {
        bf16x8 c = cvt8(v[2 * j], v[2 * j + 1]);
        int chunk = (sh * 4 + j) ^ (sr & 7);
        *(bf16x8*)(As + sr * 128 + chunk * 16) = c;
      }
    }
    {
      const float4* p = (const float4*)(bptr + kb * 64);
      float4 u[8];
#pragma unroll
      for (int j = 0; j < 8; ++j) u[j] = p[j];
#pragma unroll
      for (int j = 0; j < 4; ++j) {
        bf16x8 c = cvt8(u[2 * j], u[2 * j + 1]);
        int chunk = (sh * 4 + j) ^ (sr & 7);
        *(bf16x8*)(Bs + sr * 128 + chunk * 16) = c;
      }
    }
    __syncthreads();
#pragma unroll
    for (int ks = 0; ks < 2; ++ks) {
      bf16x8 afr[4], bfv[4];
#pragma unroll
      for (int mt = 0; mt < 4; ++mt) {
        int r = wm * 64 + mt * 16 + (lane & 15);
        int chunk = (ks * 4 + (lane >> 4)) ^ (r & 7);
        afr[mt] = *(const bf16x8*)(As + r * 128 + chunk * 16);
      }
#pragma unroll
      for (int nt = 0; nt < 4; ++nt) {
        int r = wn * 64 + nt * 16 + (lane & 15);
        int chunk = (ks * 4 + (lane >> 4)) ^ (r & 7);
        bfv[nt] = *(const bf16x8*)(Bs + r * 128 + chunk * 16);
      }
#pragma unroll
      for (int mt = 0; mt < 4; ++mt)
#pragma unroll
        for (int nt = 0; nt < 4; ++nt)
          acc[mt][nt] = __builtin_amdgcn_mfma_f32_16x16x32_bf16(
              afr[mt], bfv[nt], acc[mt][nt], 0, 0, 0);
    }
    __syncthreads();
  }
#pragma unroll
  for (int mt = 0; mt < 4; ++mt) {
#pragma unroll
    for (int j = 0; j < 4; ++j) {
      int r = wm * 64 + mt * 16 + (lane >> 4) * 4 + j;
      if (r < rows) {
        float* op = out + (size_t)(row0 + r) * NDIM + col0 + wn * 64 + (lane & 15);
#pragma unroll
        for (int nt = 0; nt < 4; ++nt) op[nt * 16] = acc[mt][nt][j];
      }
    }
  }
}

extern "C" void kernel_launch(void* const* d_in, const int* in_sizes, int n_in,
                              void* d_out, int out_size, void* d_ws, size_t ws_size,
                              hipStream_t stream) {
  const float* x = (const float*)d_in[0];
  const float* w = (const float*)d_in[1];
  const int* ms = (const int*)d_in[2];
  float* out = (float*)d_out;
  const size_t nx = (size_t)M_TOTAL * KDIM;
  const size_t nw = (size_t)NEXP * NDIM * KDIM;
  const size_t need = (nx + nw) * sizeof(__hip_bfloat16);
  if (ws_size >= need) {
    __hip_bfloat16* xb = (__hip_bfloat16*)d_ws;
    __hip_bfloat16* wb = xb + nx;
    cvt_both<<<2048, 256, 0, stream>>>(x, w, (bf16x8*)xb, (bf16x8*)wb);
    moe_gemm_8p<<<dim3(NWG), dim3(512), 0, stream>>>(xb, wb, ms, out);
  } else {
    moe_gemm_f32<<<dim3(16, 135), dim3(256), 0, stream>>>(x, w, ms, out);
  }
}